// Round 8
// baseline (220.569 us; speedup 1.0000x reference)
//
#include <hip/hip_runtime.h>
#include <hip/hip_bf16.h>
#include <cmath>

using bf16 = __hip_bfloat16;
typedef __attribute__((ext_vector_type(4))) float  f32x4;
typedef __attribute__((ext_vector_type(8))) short  bf16x8;
typedef unsigned int u32;
typedef unsigned short u16;

// async global->LDS, 16B per lane
__device__ __forceinline__ void gl_lds16(const bf16* g, bf16* l) {
    __builtin_amdgcn_global_load_lds(
        (const __attribute__((address_space(1))) u32*)g,
        (__attribute__((address_space(3))) u32*)l, 16, 0, 0);
}
__device__ __forceinline__ u32 pk2(float a, float b) {
    bf16 ha = __float2bfloat16(a), hb = __float2bfloat16(b);
    return (u32)*(u16*)&ha | ((u32)*(u16*)&hb << 16);
}
__device__ __forceinline__ float b2f(u16 v) {
    return __uint_as_float((u32)v << 16);
}

// ---------------------------------------------------------------------------
// Fused setup: blocks 0-255: WQF row; 256-319: weight bf16 convert;
// 320-351: zero sums.
// ---------------------------------------------------------------------------
__global__ __launch_bounds__(256) void wqfconv(
    const float* __restrict__ Wq, const float* __restrict__ Wk,
    const float* __restrict__ Wv, const float* __restrict__ Wffn,
    bf16* __restrict__ Wb,     // [4][65536]: q,k,v,f
    bf16* __restrict__ WQF,    // [256][256]
    float* __restrict__ sums)  // [8192]
{
    const int bx = blockIdx.x, t = threadIdx.x;
    if (bx < 256) {
        float acc = Wq[bx * 256 + t];
#pragma unroll 8
        for (int i = 0; i < 256; ++i)
            acc += Wffn[bx * 256 + i] * Wq[i * 256 + t];
        WQF[bx * 256 + t] = __float2bfloat16(acc);
    } else if (bx < 320) {
#pragma unroll
        for (int k = 0; k < 16; ++k) {
            int idx = (bx - 256) * 4096 + k * 256 + t;
            int which = idx >> 16, off = idx & 65535;
            const float* s = (which == 0) ? Wq : (which == 1) ? Wk
                           : (which == 2) ? Wv : Wffn;
            Wb[idx] = __float2bfloat16(s[off]);
        }
    } else {
        sums[(bx - 320) * 256 + t] = 0.f;
    }
}

// ---------------------------------------------------------------------------
// Q projection (8 waves), fused transpose-convert; dual-writes xbf (s-major);
// coalesced qch epilogue through LDS.
// grid (32 s-tiles, 16 b), block 512.
// ---------------------------------------------------------------------------
__global__ __launch_bounds__(512) void qproj8(
    const float* __restrict__ x,   // [16][256][4096]
    const bf16* __restrict__ Wq,   // [256][256]
    bf16* __restrict__ qch,        // [16][256][4096]
    bf16* __restrict__ xbf)        // [16][4096][256]
{
    __shared__ __align__(16) bf16 sW[256 * 64];  // 32 KB; reused as epilogue buffer
    __shared__ __align__(16) bf16 sX[128 * 72];
    const int t = threadIdx.x;
    const int lane = t & 63, wid = t >> 6;
    const int wm = wid >> 1, wn = wid & 1;
    const int g = lane >> 4, lr = lane & 15;
    const int s0 = blockIdx.x * 128;
    const int b = blockIdx.y;
    const float* xb = x + (long)b * 1048576;
    bf16* xob = xbf + (long)b * 1048576;

    f32x4 acc[4][4];
#pragma unroll
    for (int i = 0; i < 4; ++i)
#pragma unroll
        for (int j = 0; j < 4; ++j) acc[i][j] = (f32x4){0.f, 0.f, 0.f, 0.f};

    const int p  = t & 31;
    const int sl = t >> 5;

    for (int c0 = 0; c0 < 256; c0 += 64) {
        __syncthreads();
#pragma unroll
        for (int i = 0; i < 4; ++i) {
            int lin = i * 512 + t, r = lin >> 3, ch = lin & 7;
            gl_lds16(Wq + (long)r * 256 + c0 + ((ch ^ (r & 7)) << 3), &sW[lin * 8]);
        }
#pragma unroll
        for (int j = 0; j < 2; ++j) {
            int s4 = j * 16 + sl;
            const float* src = xb + (long)(c0 + 2 * p) * 4096 + s0 + s4 * 4;
            float4 a = *(const float4*)src;
            float4 bq = *(const float4*)(src + 4096);
            u32 w0 = pk2(a.x, bq.x), w1 = pk2(a.y, bq.y);
            u32 w2 = pk2(a.z, bq.z), w3 = pk2(a.w, bq.w);
            char* base = (char*)sX + p * 4 + (s4 * 4) * 144;
            *(u32*)(base +   0) = w0;
            *(u32*)(base + 144) = w1;
            *(u32*)(base + 288) = w2;
            *(u32*)(base + 432) = w3;
            long xo = (long)(s0 + s4 * 4) * 256 + c0 + 2 * p;
            *(u32*)(xob + xo)       = w0;
            *(u32*)(xob + xo + 256) = w1;
            *(u32*)(xob + xo + 512) = w2;
            *(u32*)(xob + xo + 768) = w3;
        }
        __syncthreads();
#pragma unroll
        for (int kk = 0; kk < 2; ++kk) {
            bf16x8 aw[4], fx[4];
#pragma unroll
            for (int mf = 0; mf < 4; ++mf) {
                int r = wm * 64 + mf * 16 + lr;
                aw[mf] = *(const bf16x8*)((const char*)sW + r * 128 + (((kk * 4 + g) ^ (r & 7)) << 4));
            }
#pragma unroll
            for (int nf = 0; nf < 4; ++nf) {
                int s = wn * 64 + nf * 16 + lr;
                fx[nf] = *(const bf16x8*)((const char*)sX + s * 144 + (kk * 4 + g) * 16);
            }
#pragma unroll
            for (int mf = 0; mf < 4; ++mf)
#pragma unroll
                for (int nf = 0; nf < 4; ++nf)
                    acc[mf][nf] = __builtin_amdgcn_mfma_f32_16x16x32_bf16(
                        aw[mf], fx[nf], acc[mf][nf], 0, 0, 0);
        }
    }
    // coalesced epilogue: two 128-row halves through sW (XOR-swizzled)
    bf16* qb = qch + (long)b * 1048576;
#pragma unroll
    for (int h = 0; h < 2; ++h) {
        __syncthreads();   // sW (or prior half) reads complete
        if ((wm >> 1) == h) {
#pragma unroll
            for (int mf = 0; mf < 4; ++mf)
#pragma unroll
                for (int nf = 0; nf < 4; ++nf)
#pragma unroll
                    for (int e = 0; e < 4; ++e) {
                        int ol = (wm & 1) * 64 + mf * 16 + g * 4 + e;  // 0..127
                        int s = wn * 64 + nf * 16 + lr;
                        bf16 hv = __float2bfloat16(acc[mf][nf][e]);
                        int byte = (ol * 256 + s * 2) ^ ((ol & 7) << 4);
                        *(u16*)((char*)sW + byte) = *(u16*)&hv;
                    }
        }
        __syncthreads();
#pragma unroll
        for (int i = 0; i < 4; ++i) {
            int lin = i * 512 + t, r = lin >> 4, c = lin & 15;
            uint4 v = *(const uint4*)((const char*)sW + r * 256 + (((c ^ (r & 7))) << 4));
            *(uint4*)(qb + (long)(h * 128 + r) * 4096 + s0 + c * 8) = v;
        }
    }
}

// ---------------------------------------------------------------------------
// Fused K/V projection + QK^T partial + sumsq.  k never hits HBM.
// grid (8 s-chunks of 512, 64 bn), block 256 (4 waves).
// LDS (50 KB): region A [0,34816): P1 = sF[128][72]; P2 = sKt(16K)+sVst[128][72]
//              region W [34816,51200): sWk 8K + sWv 8K
// ---------------------------------------------------------------------------
__global__ __launch_bounds__(256) void kvqk(
    const float* __restrict__ fm,   // [64][256][4096]
    const bf16* __restrict__ Wk,    // [4][64][256]
    const bf16* __restrict__ Wv,    // [4][64][256]
    const bf16* __restrict__ qch,   // [16][256][4096]
    bf16* __restrict__ vT,          // [64][4096][64]
    float* __restrict__ part,       // [64][8][64][64]
    float* __restrict__ sums)       // [0:4096) sumq, [4096:8192) sumk
{
    __shared__ __align__(16) char smem[51200];
    bf16* sF  = (bf16*)smem;              // P1
    bf16* sWk = (bf16*)(smem + 34816);
    bf16* sWv = (bf16*)(smem + 43008);
    // P2: sKt at smem[0..16384), sVst at smem[16384..34816)

    const int t = threadIdx.x;
    const int lane = t & 63, wid = t >> 6;
    const int g = lane >> 4, lr = lane & 15;
    const int ch_ = blockIdx.x;     // 0..7
    const int bn = blockIdx.y, n = bn & 3;
    const float* fb = fm + (long)bn * 1048576;
    const bf16* WkN = Wk + (long)n * 16384;
    const bf16* WvN = Wv + (long)n * 16384;
    const bf16* qbase = qch + (long)bn * 262144;
    bf16* vtb = vT + (long)bn * 262144;

    const int p  = t & 31;
    const int sl = t >> 5;

    f32x4 accQ[4];
#pragma unroll
    for (int i = 0; i < 4; ++i) accQ[i] = (f32x4){0.f, 0.f, 0.f, 0.f};
    float kss[4][4];
#pragma unroll
    for (int i = 0; i < 4; ++i)
#pragma unroll
        for (int j = 0; j < 4; ++j) kss[i][j] = 0.f;
    float qss[4] = {0.f, 0.f, 0.f, 0.f};

    for (int sub = 0; sub < 4; ++sub) {
        const int ss0 = ch_ * 512 + sub * 128;
        f32x4 acc1[4][2], acc2[2][4];
#pragma unroll
        for (int i = 0; i < 4; ++i)
#pragma unroll
            for (int j = 0; j < 2; ++j) {
                acc1[i][j] = (f32x4){0.f, 0.f, 0.f, 0.f};
                acc2[j][i] = (f32x4){0.f, 0.f, 0.f, 0.f};
            }

        for (int c0 = 0; c0 < 256; c0 += 64) {
            __syncthreads();   // region A writable (prior MFMA / P2 reads done)
#pragma unroll
            for (int i = 0; i < 2; ++i) {
                int lin = i * 256 + t, r = lin >> 3, c = lin & 7;
                int off = r * 256 + c0 + ((c ^ (r & 7)) << 3);
                gl_lds16(WkN + off, &sWk[lin * 8]);
                gl_lds16(WvN + off, &sWv[lin * 8]);
            }
#pragma unroll
            for (int j = 0; j < 4; ++j) {
                int s4 = j * 8 + sl;
                const float* src = fb + (long)(c0 + 2 * p) * 4096 + ss0 + s4 * 4;
                float4 a = *(const float4*)src;
                float4 bq = *(const float4*)(src + 4096);
                char* base = (char*)sF + p * 4 + (s4 * 4) * 144;
                *(u32*)(base +   0) = pk2(a.x, bq.x);
                *(u32*)(base + 144) = pk2(a.y, bq.y);
                *(u32*)(base + 288) = pk2(a.z, bq.z);
                *(u32*)(base + 432) = pk2(a.w, bq.w);
            }
            __syncthreads();
#pragma unroll
            for (int kk = 0; kk < 2; ++kk) {
                bf16x8 ak[4], ff[2], bv[4];
#pragma unroll
                for (int mf = 0; mf < 4; ++mf) {
                    int r = mf * 16 + lr;
                    ak[mf] = *(const bf16x8*)((const char*)sWk + r * 128 + (((kk * 4 + g) ^ (r & 7)) << 4));
                }
#pragma unroll
                for (int i = 0; i < 2; ++i) {
                    int s = wid * 32 + i * 16 + lr;
                    ff[i] = *(const bf16x8*)((const char*)sF + s * 144 + (kk * 4 + g) * 16);
                }
#pragma unroll
                for (int nf = 0; nf < 4; ++nf) {
                    int r = nf * 16 + lr;
                    bv[nf] = *(const bf16x8*)((const char*)sWv + r * 128 + (((kk * 4 + g) ^ (r & 7)) << 4));
                }
#pragma unroll
                for (int mf = 0; mf < 4; ++mf)
#pragma unroll
                    for (int i = 0; i < 2; ++i)
                        acc1[mf][i] = __builtin_amdgcn_mfma_f32_16x16x32_bf16(
                            ak[mf], ff[i], acc1[mf][i], 0, 0, 0);
#pragma unroll
                for (int i = 0; i < 2; ++i)
#pragma unroll
                    for (int nf = 0; nf < 4; ++nf)
                        acc2[i][nf] = __builtin_amdgcn_mfma_f32_16x16x32_bf16(
                            ff[i], bv[nf], acc2[i][nf], 0, 0, 0);
            }
        }
        // ---- P2 ----
        __syncthreads();   // all sF reads done; region A reusable
        // k -> sKt (swizzled u16) + k-sumsq from f32 accumulators
#pragma unroll
        for (int mf = 0; mf < 4; ++mf)
#pragma unroll
            for (int i = 0; i < 2; ++i)
#pragma unroll
                for (int e = 0; e < 4; ++e) {
                    int dd = mf * 16 + g * 4 + e;
                    int sc = wid * 32 + i * 16 + lr;
                    float f = acc1[mf][i][e];
                    kss[mf][e] += f * f;
                    bf16 hv = __float2bfloat16(f);
                    int byte = (dd * 256 + sc * 2) ^ ((dd & 7) << 4);
                    *(u16*)(smem + byte) = *(u16*)&hv;
                }
        // v -> sVst [s][72] (u16 scatter)
#pragma unroll
        for (int i = 0; i < 2; ++i)
#pragma unroll
            for (int nf = 0; nf < 4; ++nf)
#pragma unroll
                for (int e = 0; e < 4; ++e) {
                    int slc = wid * 32 + i * 16 + g * 4 + e;
                    int ec = nf * 16 + lr;
                    bf16 hv = __float2bfloat16(acc2[i][nf][e]);
                    *(u16*)(smem + 16384 + slc * 144 + ec * 2) = *(u16*)&hv;
                }
        __syncthreads();   // sKt / sVst visible
        // QK: A from sKt, B fragments direct from global qch
#pragma unroll
        for (int kks = 0; kks < 4; ++kks) {
            int rA = wid * 16 + lr;
            bf16x8 af = *(const bf16x8*)(smem + rA * 256 + (((kks * 4 + g) ^ (rA & 7)) << 4));
            bf16x8 bq[4];
#pragma unroll
            for (int nf = 0; nf < 4; ++nf) {
                int rB = nf * 16 + lr;
                bq[nf] = *(const bf16x8*)(qbase + (long)rB * 4096 + ss0 + (kks * 4 + g) * 8);
            }
#pragma unroll
            for (int nf = 0; nf < 4; ++nf) {
                accQ[nf] = __builtin_amdgcn_mfma_f32_16x16x32_bf16(
                    af, bq[nf], accQ[nf], 0, 0, 0);
#pragma unroll
                for (int e2 = 0; e2 < 8; ++e2) {
                    float f = b2f((u16)bq[nf][e2]);
                    qss[nf] += f * f;
                }
            }
        }
        // coalesced v store: sVst rows -> vT (1 KB contiguous per wave instr)
#pragma unroll
        for (int i2 = 0; i2 < 4; ++i2) {
            int lin = i2 * 256 + t, r = lin >> 3, c = lin & 7;
            uint4 v = *(const uint4*)(smem + 16384 + r * 144 + c * 16);
            *(uint4*)(vtb + (long)(ss0 + r) * 64 + c * 8) = v;
        }
    }
    // part write
    float* pp = part + ((long)bn * 8 + ch_) * 4096;
#pragma unroll
    for (int nf = 0; nf < 4; ++nf)
#pragma unroll
        for (int e = 0; e < 4; ++e) {
            int dd = wid * 16 + g * 4 + e;
            pp[dd * 64 + nf * 16 + lr] = accQ[nf][e];
        }
    // k-sumsq: reduce over lr lanes, atomic per (g,mf,e)
#pragma unroll
    for (int mf = 0; mf < 4; ++mf)
#pragma unroll
        for (int e = 0; e < 4; ++e) {
            float v = kss[mf][e];
            v += __shfl_xor(v, 1);
            v += __shfl_xor(v, 2);
            v += __shfl_xor(v, 4);
            v += __shfl_xor(v, 8);
            if (lr == 0)
                atomicAdd(&sums[4096 + bn * 64 + mf * 16 + g * 4 + e], v);
        }
    // q-sumsq: reduce over g lanes (all waves computed identical copies)
#pragma unroll
    for (int nf = 0; nf < 4; ++nf) {
        float v = qss[nf];
        v += __shfl_xor(v, 16);
        v += __shfl_xor(v, 32);
        if (wid == 0 && g == 0)
            atomicAdd(&sums[bn * 64 + nf * 16 + lr], v);
    }
}

// ---------------------------------------------------------------------------
// finalize: sum partials, rsqrt norms, softmax, then M2 = Wffn_head @ P.
// grid 64 (bn), block 256.  M2[b][c][n*64+e] bf16.
// ---------------------------------------------------------------------------
__global__ __launch_bounds__(256) void finalizeM2(
    const float* __restrict__ part, const float* __restrict__ sums,
    const float* __restrict__ rescale, const bf16* __restrict__ Wf,
    bf16* __restrict__ M2)
{
    __shared__ float att[64][65];
    __shared__ float rmax[64], rsm[64], iq[64], ik[64];
    __shared__ __align__(16) bf16 sWf[256 * 64];
    __shared__ __align__(16) bf16 attT[64 * 64];
    const int bn = blockIdx.x, n = bn & 3, b = bn >> 2;
    const int t = threadIdx.x;
    const int lane = t & 63, wid = t >> 6;
    const int g = lane >> 4, lr = lane & 15;
    const float rs = rescale[n];

#pragma unroll
    for (int i = 0; i < 8; ++i) {
        int lin = i * 256 + t, r = lin >> 3, c = lin & 7;
        gl_lds16(Wf + (long)r * 256 + n * 64 + ((c ^ (r & 7)) << 3), &sWf[lin * 8]);
    }
    if (t < 64)        ik[t]      = 1.f / fmaxf(sqrtf(sums[4096 + bn * 64 + t]), 1e-12f);
    else if (t < 128)  iq[t - 64] = 1.f / fmaxf(sqrtf(sums[bn * 64 + t - 64]), 1e-12f);
    __syncthreads();

    const float* pb = part + (long)bn * 8 * 4096;
#pragma unroll
    for (int p_ = 0; p_ < 16; ++p_) {
        int lin = p_ * 256 + t;
        int dd = lin >> 6, e = lin & 63;
        float v = 0.f;
#pragma unroll
        for (int c = 0; c < 8; ++c) v += pb[c * 4096 + lin];
        att[dd][e] = v * ik[dd] * iq[e] * rs;
    }
    __syncthreads();
    if (t < 64) {
        float m = -1e30f;
        for (int e = 0; e < 64; ++e) m = fmaxf(m, att[t][e]);
        float sm = 0.f;
        for (int e = 0; e < 64; ++e) sm += expf(att[t][e] - m);
        rmax[t] = m;
        rsm[t] = 1.0f / sm;
    }
    __syncthreads();
#pragma unroll
    for (int p_ = 0; p_ < 16; ++p_) {
        int lin = p_ * 256 + t;
        int dd = lin >> 6, e = lin & 63;
        bf16 hv = __float2bfloat16(expf(att[dd][e] - rmax[dd]) * rsm[dd]);
        int byte = (e * 128 + dd * 2) ^ ((e & 7) << 4);
        *(u16*)((char*)attT + byte) = *(u16*)&hv;
    }
    __syncthreads();

    f32x4 acc[4][4];
#pragma unroll
    for (int i = 0; i < 4; ++i)
#pragma unroll
        for (int j = 0; j < 4; ++j) acc[i][j] = (f32x4){0.f, 0.f, 0.f, 0.f};
#pragma unroll
    for (int kk = 0; kk < 2; ++kk) {
        bf16x8 aw[4], bt[4];
#pragma unroll
        for (int mf = 0; mf < 4; ++mf) {
            int r = wid * 64 + mf * 16 + lr;
            aw[mf] = *(const bf16x8*)((const char*)sWf + r * 128 + (((kk * 4 + g) ^ (r & 7)) << 4));
        }
#pragma unroll
        for (int nf = 0; nf < 4; ++nf) {
            int e = nf * 16 + lr;
            bt[nf] = *(const bf16x8*)((const char*)attT + e * 128 + (((kk * 4 + g) ^ (e & 7)) << 4));
        }
#pragma unroll
        for (int mf = 0; mf < 4; ++mf)
#pragma unroll
            for (int nf = 0; nf < 4; ++nf)
                acc[mf][nf] = __builtin_amdgcn_mfma_f32_16x16x32_bf16(
                    aw[mf], bt[nf], acc[mf][nf], 0, 0, 0);
    }
    bf16* m2b = M2 + (long)b * 65536;
#pragma unroll
    for (int mf = 0; mf < 4; ++mf)
#pragma unroll
        for (int nf = 0; nf < 4; ++nf)
#pragma unroll
            for (int e = 0; e < 4; ++e) {
                int c = wid * 64 + mf * 16 + g * 4 + e;
                m2b[c * 256 + n * 64 + nf * 16 + lr] = __float2bfloat16(acc[mf][nf][e]);
            }
}

// ---------------------------------------------------------------------------
// out[b][c][s] = sum_e' M2[b][c][e'] v[b][e'][s] + sum_c' WQF[c][c'] x[c'][s]
//              + bffn[c]
// grid (32 s-tiles, 16 b), block 512.
// ---------------------------------------------------------------------------
__global__ __launch_bounds__(512) void outgemm(
    const bf16* __restrict__ M2,   // [16][256][256]
    const bf16* __restrict__ WQF,  // [256][256]
    const bf16* __restrict__ vT,   // [64][4096][64]
    const bf16* __restrict__ xbf,  // [16][4096][256]
    const float* __restrict__ bffn,
    float* __restrict__ out)       // [16][256][4096]
{
    __shared__ __align__(16) bf16 sA[256 * 64];
    __shared__ __align__(16) bf16 sB[128 * 64];
    const int t = threadIdx.x;
    const int lane = t & 63, wid = t >> 6;
    const int wm = wid >> 1, wn = wid & 1;
    const int g = lane >> 4, lr = lane & 15;
    const int s0 = blockIdx.x * 128;
    const int b = blockIdx.y;

    f32x4 acc[4][4];
#pragma unroll
    for (int i = 0; i < 4; ++i)
#pragma unroll
        for (int j = 0; j < 4; ++j) acc[i][j] = (f32x4){0.f, 0.f, 0.f, 0.f};

    for (int ch = 0; ch < 8; ++ch) {
        const bf16* Asrc;
        const bf16* Bsrc;
        int Brs;
        if (ch < 4) {
            Asrc = M2 + (long)b * 65536 + ch * 64;
            Bsrc = vT + ((long)b * 4 + ch) * 262144 + (long)s0 * 64;
            Brs = 64;
        } else {
            Asrc = WQF + (ch - 4) * 64;
            Bsrc = xbf + (long)b * 1048576 + (long)s0 * 256 + (ch - 4) * 64;
            Brs = 256;
        }
        __syncthreads();
#pragma unroll
        for (int i = 0; i < 4; ++i) {
            int lin = i * 512 + t, r = lin >> 3, c = lin & 7;
            gl_lds16(Asrc + (long)r * 256 + ((c ^ (r & 7)) << 3), &sA[lin * 8]);
        }
#pragma unroll
        for (int i = 0; i < 2; ++i) {
            int lin = i * 512 + t, r = lin >> 3, c = lin & 7;
            gl_lds16(Bsrc + (long)r * Brs + ((c ^ (r & 7)) << 3), &sB[lin * 8]);
        }
        __syncthreads();
#pragma unroll
        for (int kk = 0; kk < 2; ++kk) {
            bf16x8 aw[4], bz[4];
#pragma unroll
            for (int mf = 0; mf < 4; ++mf) {
                int r = wm * 64 + mf * 16 + lr;
                aw[mf] = *(const bf16x8*)((const char*)sA + r * 128 + (((kk * 4 + g) ^ (r & 7)) << 4));
            }
#pragma unroll
            for (int nf = 0; nf < 4; ++nf) {
                int r = wn * 64 + nf * 16 + lr;
                bz[nf] = *(const bf16x8*)((const char*)sB + r * 128 + (((kk * 4 + g) ^ (r & 7)) << 4));
            }
#pragma unroll
            for (int mf = 0; mf < 4; ++mf)
#pragma unroll
                for (int nf = 0; nf < 4; ++nf)
                    acc[mf][nf] = __builtin_amdgcn_mfma_f32_16x16x32_bf16(
                        aw[mf], bz[nf], acc[mf][nf], 0, 0, 0);
        }
    }
    float* ob = out + (long)b * 1048576;
#pragma unroll
    for (int mf = 0; mf < 4; ++mf)
#pragma unroll
        for (int e = 0; e < 4; ++e) {
            int c = wm * 64 + mf * 16 + g * 4 + e;
            float bv = bffn[c];
#pragma unroll
            for (int nf = 0; nf < 4; ++nf) {
                int s = s0 + wn * 64 + nf * 16 + lr;
                ob[(long)c * 4096 + s] = acc[mf][nf][e] + bv;
            }
        }
}

// ---------------------------------------------------------------------------
extern "C" void kernel_launch(void* const* d_in, const int* in_sizes, int n_in,
                              void* d_out, int out_size, void* d_ws, size_t ws_size,
                              hipStream_t stream) {
    const float* x       = (const float*)d_in[0];
    const float* fmaps   = (const float*)d_in[1];
    const float* Wq      = (const float*)d_in[2];
    const float* Wk      = (const float*)d_in[3];
    const float* Wv      = (const float*)d_in[4];
    const float* rescale = (const float*)d_in[5];
    const float* Wffn    = (const float*)d_in[6];
    const float* bffn    = (const float*)d_in[7];
    float* out = (float*)d_out;

    char* w = (char*)d_ws;
    bf16* qch   = (bf16*)(w + 0);             //  33.55 MB
    bf16* vT    = (bf16*)(w + 33554432L);     //  33.55 MB
    bf16* xbf   = (bf16*)(w + 67108864L);     //  33.55 MB
    float* part = (float*)(w + 100663296L);   //   8.39 MB
    float* sums = (float*)(w + 109051904L);   //  32 KB
    bf16* M2    = (bf16*)(w + 109084672L);    //   2 MB
    bf16* Wb    = (bf16*)(w + 111181824L);    // 4 x 128 KB (q,k,v,f)
    bf16* Wq_b  = Wb;
    bf16* Wk_b  = Wb + 65536;
    bf16* Wv_b  = Wb + 131072;
    bf16* Wf_b  = Wb + 196608;
    bf16* WQF   = (bf16*)(w + 111706112L);    // 128 KB

    dim3 blk(256);

    // 1. weights -> bf16, WQF = Wffn@Wq + Wq, zero sums (one launch)
    wqfconv<<<dim3(352), blk, 0, stream>>>(Wq, Wk, Wv, Wffn, Wb, WQF, sums);
    // 2. Q projection + xbf (coalesced epilogue)
    qproj8<<<dim3(32, 16), dim3(512), 0, stream>>>(x, Wq_b, qch, xbf);
    // 3. fused K/V proj + QK^T + sumsq (coalesced vT, direct-global q frags)
    kvqk<<<dim3(8, 64), blk, 0, stream>>>(fmaps, Wk_b, Wv_b, qch, vT, part, sums);
    // 4. softmax + M2
    finalizeM2<<<dim3(64), blk, 0, stream>>>(part, sums, rescale, Wf_b, M2);
    // 5. final fused GEMM
    outgemm<<<dim3(32, 16), dim3(512), 0, stream>>>(M2, WQF, vT, xbf, bffn, out);
}

// Round 9
// 183.993 us; speedup vs baseline: 1.1988x; 1.1988x over previous
//
#include <hip/hip_runtime.h>
#include <hip/hip_bf16.h>
#include <cmath>

using bf16 = __hip_bfloat16;
typedef __attribute__((ext_vector_type(4))) float  f32x4;
typedef __attribute__((ext_vector_type(8))) short  bf16x8;
typedef unsigned int u32;
typedef unsigned short u16;

// async global->LDS, 16B per lane
__device__ __forceinline__ void gl_lds16(const bf16* g, bf16* l) {
    __builtin_amdgcn_global_load_lds(
        (const __attribute__((address_space(1))) u32*)g,
        (__attribute__((address_space(3))) u32*)l, 16, 0, 0);
}

__device__ __forceinline__ u32 pk2(float a, float b) {
    bf16 ha = __float2bfloat16(a), hb = __float2bfloat16(b);
    return (u32)*(u16*)&ha | ((u32)*(u16*)&hb << 16);
}
__device__ __forceinline__ float b2f(u16 v) {
    return __uint_as_float((u32)v << 16);
}

// ---------------------------------------------------------------------------
// Q projection: full 256-o tile (x read ONCE), fused transpose-convert.
// qch[b][o][s] = sum_c Wq[o][c] x[b][c][s]
// grid (32 s-tiles, 16 b), block 512: waves (wm 0..3 -> 64 o, wn 0..1 -> 64 s)
// ---------------------------------------------------------------------------
__global__ __launch_bounds__(512) void qproj8(
    const float* __restrict__ x,   // [16][256][4096]
    const bf16* __restrict__ Wq,   // [256][256]
    bf16* __restrict__ qch)        // [16][256][4096]
{
    __shared__ __align__(16) bf16 sW[256 * 64];  // [o][64c] chunk-XOR swizzled
    __shared__ __align__(16) bf16 sX[128 * 72];  // [s][c], 144B rows
    const int t = threadIdx.x;
    const int lane = t & 63, wid = t >> 6;
    const int wm = wid >> 1, wn = wid & 1;
    const int g = lane >> 4, lr = lane & 15;
    const int s0 = blockIdx.x * 128;
    const int b = blockIdx.y;
    const float* xb = x + (long)b * 1048576;

    f32x4 acc[4][4];
#pragma unroll
    for (int i = 0; i < 4; ++i)
#pragma unroll
        for (int j = 0; j < 4; ++j) acc[i][j] = (f32x4){0.f, 0.f, 0.f, 0.f};

    const int p  = t & 31;   // c-pair
    const int sl = t >> 5;   // 0..15

    for (int c0 = 0; c0 < 256; c0 += 64) {
        __syncthreads();
#pragma unroll
        for (int i = 0; i < 4; ++i) {
            int lin = i * 512 + t, r = lin >> 3, ch = lin & 7;
            gl_lds16(Wq + (long)r * 256 + c0 + ((ch ^ (r & 7)) << 3), &sW[lin * 8]);
        }
#pragma unroll
        for (int j = 0; j < 2; ++j) {
            int s4 = j * 16 + sl;   // 0..31
            const float* src = xb + (long)(c0 + 2 * p) * 4096 + s0 + s4 * 4;
            float4 a = *(const float4*)src;
            float4 bq = *(const float4*)(src + 4096);
            char* base = (char*)sX + p * 4 + (s4 * 4) * 144;
            *(u32*)(base +   0) = pk2(a.x, bq.x);
            *(u32*)(base + 144) = pk2(a.y, bq.y);
            *(u32*)(base + 288) = pk2(a.z, bq.z);
            *(u32*)(base + 432) = pk2(a.w, bq.w);
        }
        __syncthreads();
#pragma unroll
        for (int kk = 0; kk < 2; ++kk) {
            bf16x8 aw[4], fx[4];
#pragma unroll
            for (int mf = 0; mf < 4; ++mf) {
                int r = wm * 64 + mf * 16 + lr;
                aw[mf] = *(const bf16x8*)((const char*)sW + r * 128 + (((kk * 4 + g) ^ (r & 7)) << 4));
            }
#pragma unroll
            for (int nf = 0; nf < 4; ++nf) {
                int s = wn * 64 + nf * 16 + lr;
                fx[nf] = *(const bf16x8*)((const char*)sX + s * 144 + (kk * 4 + g) * 16);
            }
#pragma unroll
            for (int mf = 0; mf < 4; ++mf)
#pragma unroll
                for (int nf = 0; nf < 4; ++nf)
                    acc[mf][nf] = __builtin_amdgcn_mfma_f32_16x16x32_bf16(
                        aw[mf], fx[nf], acc[mf][nf], 0, 0, 0);
        }
    }
    bf16* qb = qch + (long)b * 1048576;
#pragma unroll
    for (int mf = 0; mf < 4; ++mf)
#pragma unroll
        for (int nf = 0; nf < 4; ++nf)
#pragma unroll
            for (int e = 0; e < 4; ++e) {
                int o = wm * 64 + mf * 16 + g * 4 + e;
                int s = s0 + wn * 64 + nf * 16 + lr;
                qb[(long)o * 4096 + s] = __float2bfloat16(acc[mf][nf][e]);
            }
}

// ---------------------------------------------------------------------------
// K+V projection, fused transpose-convert of fmaps, double-buffered. (R5)
// grid (32 s-tiles, 64 bn), block 256.
// ---------------------------------------------------------------------------
__global__ __launch_bounds__(256) void kvproj(
    const float* __restrict__ fm,  // [64][256][4096]
    const bf16* __restrict__ Wk,   // [4][64][256]
    const bf16* __restrict__ Wv,   // [4][64][256]
    bf16* __restrict__ kb,         // [64][64][4096]
    bf16* __restrict__ vT)         // [64][4096][64]
{
    __shared__ bf16 sF[2][128 * 72];
    __shared__ bf16 sK[2][64 * 64];
    __shared__ bf16 sV[2][64 * 64];
    const int t = threadIdx.x;
    const int lane = t & 63, wid = t >> 6;
    const int g = lane >> 4, lr = lane & 15;
    const int s0 = blockIdx.x * 128;
    const int bn = blockIdx.y, n = bn & 3;
    const float* fb = fm + (long)bn * 1048576;
    const bf16* WkN = Wk + (long)n * 16384;
    const bf16* WvN = Wv + (long)n * 16384;

    f32x4 acc1[4][2];
    f32x4 acc2[2][4];
#pragma unroll
    for (int i = 0; i < 4; ++i)
#pragma unroll
        for (int j = 0; j < 2; ++j) {
            acc1[i][j] = (f32x4){0.f, 0.f, 0.f, 0.f};
            acc2[j][i] = (f32x4){0.f, 0.f, 0.f, 0.f};
        }

    const int p  = t & 31;
    const int sl = t >> 5;

    // prologue: stage c0=0 into buf 0
    {
#pragma unroll
        for (int i = 0; i < 2; ++i) {
            int lin = i * 256 + t, r = lin >> 3, ch = lin & 7;
            int off = r * 256 + ((ch ^ (r & 7)) << 3);
            gl_lds16(WkN + off, &sK[0][lin * 8]);
            gl_lds16(WvN + off, &sV[0][lin * 8]);
        }
        float4 ra[4], rb[4];
#pragma unroll
        for (int j = 0; j < 4; ++j) {
            const float* src = fb + (long)(2 * p) * 4096 + s0 + (j * 8 + sl) * 4;
            ra[j] = *(const float4*)src;
            rb[j] = *(const float4*)(src + 4096);
        }
#pragma unroll
        for (int j = 0; j < 4; ++j) {
            char* base = (char*)&sF[0][0] + p * 4 + ((j * 8 + sl) * 4) * 144;
            *(u32*)(base +   0) = pk2(ra[j].x, rb[j].x);
            *(u32*)(base + 144) = pk2(ra[j].y, rb[j].y);
            *(u32*)(base + 288) = pk2(ra[j].z, rb[j].z);
            *(u32*)(base + 432) = pk2(ra[j].w, rb[j].w);
        }
        __syncthreads();
    }

    int cur = 0;
    for (int it = 0; it < 4; ++it) {
        const int c0n = (it + 1) * 64;
        float4 ra[4], rb[4];
        if (it < 3) {
#pragma unroll
            for (int i = 0; i < 2; ++i) {
                int lin = i * 256 + t, r = lin >> 3, ch = lin & 7;
                int off = r * 256 + c0n + ((ch ^ (r & 7)) << 3);
                gl_lds16(WkN + off, &sK[cur ^ 1][lin * 8]);
                gl_lds16(WvN + off, &sV[cur ^ 1][lin * 8]);
            }
#pragma unroll
            for (int j = 0; j < 4; ++j) {
                const float* src = fb + (long)(c0n + 2 * p) * 4096 + s0 + (j * 8 + sl) * 4;
                ra[j] = *(const float4*)src;
                rb[j] = *(const float4*)(src + 4096);
            }
        }
        const char* fbase = (const char*)&sF[cur][0];
        const char* kbase = (const char*)&sK[cur][0];
        const char* vbase = (const char*)&sV[cur][0];
#pragma unroll
        for (int kk = 0; kk < 2; ++kk) {
            bf16x8 ak[4], ff[2], bv[4];
#pragma unroll
            for (int mf = 0; mf < 4; ++mf) {
                int r = mf * 16 + lr;
                ak[mf] = *(const bf16x8*)(kbase + r * 128 + (((kk * 4 + g) ^ (r & 7)) << 4));
            }
#pragma unroll
            for (int i = 0; i < 2; ++i) {
                int s = wid * 32 + i * 16 + lr;
                ff[i] = *(const bf16x8*)(fbase + s * 144 + (kk * 4 + g) * 16);
            }
#pragma unroll
            for (int nf = 0; nf < 4; ++nf) {
                int r = nf * 16 + lr;
                bv[nf] = *(const bf16x8*)(vbase + r * 128 + (((kk * 4 + g) ^ (r & 7)) << 4));
            }
#pragma unroll
            for (int mf = 0; mf < 4; ++mf)
#pragma unroll
                for (int i = 0; i < 2; ++i)
                    acc1[mf][i] = __builtin_amdgcn_mfma_f32_16x16x32_bf16(
                        ak[mf], ff[i], acc1[mf][i], 0, 0, 0);
#pragma unroll
            for (int i = 0; i < 2; ++i)
#pragma unroll
                for (int nf = 0; nf < 4; ++nf)
                    acc2[i][nf] = __builtin_amdgcn_mfma_f32_16x16x32_bf16(
                        ff[i], bv[nf], acc2[i][nf], 0, 0, 0);
        }
        if (it < 3) {
#pragma unroll
            for (int j = 0; j < 4; ++j) {
                char* base = (char*)&sF[cur ^ 1][0] + p * 4 + ((j * 8 + sl) * 4) * 144;
                *(u32*)(base +   0) = pk2(ra[j].x, rb[j].x);
                *(u32*)(base + 144) = pk2(ra[j].y, rb[j].y);
                *(u32*)(base + 288) = pk2(ra[j].z, rb[j].z);
                *(u32*)(base + 432) = pk2(ra[j].w, rb[j].w);
            }
            __syncthreads();
            cur ^= 1;
        }
    }

    bf16* kbb = kb + (long)bn * 262144;
#pragma unroll
    for (int mf = 0; mf < 4; ++mf)
#pragma unroll
        for (int i = 0; i < 2; ++i)
#pragma unroll
            for (int e = 0; e < 4; ++e) {
                int dd = mf * 16 + g * 4 + e;
                int s  = s0 + wid * 32 + i * 16 + lr;
                kbb[(long)dd * 4096 + s] = __float2bfloat16(acc1[mf][i][e]);
            }
    bf16* vtb = vT + (long)bn * 262144;
#pragma unroll
    for (int i = 0; i < 2; ++i)
#pragma unroll
        for (int nf = 0; nf < 4; ++nf)
#pragma unroll
            for (int e = 0; e < 4; ++e) {
                int s = s0 + wid * 32 + i * 16 + g * 4 + e;
                int ec = nf * 16 + lr;
                vtb[(long)s * 64 + ec] = __float2bfloat16(acc2[i][nf][e]);
            }
}

// ---------------------------------------------------------------------------
// QK^T partial + fused row sum-of-squares, 8 chunks, double-buffered. (R5)
// grid (8, 64), block 256 (4 waves 2x2, wave 32x32).
// ---------------------------------------------------------------------------
__global__ __launch_bounds__(256) void qk_sum(
    const bf16* __restrict__ kb,   // [64][64][4096]
    const bf16* __restrict__ qch,  // viewed as [64][64][4096]
    float* __restrict__ part,      // [64][8][64][64]
    float* __restrict__ sumq, float* __restrict__ sumk)  // [8][4096]
{
    __shared__ bf16 sA[2][64 * 64];
    __shared__ bf16 sB[2][64 * 64];
    const int t = threadIdx.x;
    const int lane = t & 63, wid = t >> 6;
    const int wm = wid >> 1, wn = wid & 1;
    const int g = lane >> 4, lr = lane & 15;
    const int ch_ = blockIdx.x;    // s-chunk 0..7 (512 s each)
    const int bn = blockIdx.y;
    const bf16* kbase = kb + (long)bn * 262144;
    const bf16* qbase = qch + (long)bn * 262144;

    const int srow = t >> 1;
    const int shalf = t & 1;

    f32x4 acc[2][2];
#pragma unroll
    for (int i = 0; i < 2; ++i)
#pragma unroll
        for (int j = 0; j < 2; ++j) acc[i][j] = (f32x4){0.f, 0.f, 0.f, 0.f};
    float ss = 0.f;

    {
        int k0 = ch_ * 512;
#pragma unroll
        for (int i = 0; i < 2; ++i) {
            int lin = i * 256 + t, r = lin >> 3, c = lin & 7;
            gl_lds16(kbase + (long)r * 4096 + k0 + ((c ^ (r & 7)) << 3), &sA[0][lin * 8]);
            gl_lds16(qbase + (long)r * 4096 + k0 + ((c ^ (r & 7)) << 3), &sB[0][lin * 8]);
        }
        __syncthreads();
    }

    int cur = 0;
    for (int it = 0; it < 8; ++it) {
        if (it < 7) {
            int k0 = ch_ * 512 + (it + 1) * 64;
#pragma unroll
            for (int i = 0; i < 2; ++i) {
                int lin = i * 256 + t, r = lin >> 3, c = lin & 7;
                gl_lds16(kbase + (long)r * 4096 + k0 + ((c ^ (r & 7)) << 3), &sA[cur ^ 1][lin * 8]);
                gl_lds16(qbase + (long)r * 4096 + k0 + ((c ^ (r & 7)) << 3), &sB[cur ^ 1][lin * 8]);
            }
        }
        const char* abase = (const char*)&sA[cur][0];
        const char* bbase = (const char*)&sB[cur][0];
#pragma unroll
        for (int kk = 0; kk < 2; ++kk) {
            bf16x8 af[2], bf[2];
#pragma unroll
            for (int mf = 0; mf < 2; ++mf) {
                int r = wm * 32 + mf * 16 + lr;
                af[mf] = *(const bf16x8*)(abase + r * 128 + (((kk * 4 + g) ^ (r & 7)) << 4));
            }
#pragma unroll
            for (int nf = 0; nf < 2; ++nf) {
                int r = wn * 32 + nf * 16 + lr;
                bf[nf] = *(const bf16x8*)(bbase + r * 128 + (((kk * 4 + g) ^ (r & 7)) << 4));
            }
#pragma unroll
            for (int mf = 0; mf < 2; ++mf)
#pragma unroll
                for (int nf = 0; nf < 2; ++nf)
                    acc[mf][nf] = __builtin_amdgcn_mfma_f32_16x16x32_bf16(
                        af[mf], bf[nf], acc[mf][nf], 0, 0, 0);
        }
        {
            const char* base = (srow < 64) ? abase + srow * 128
                                           : bbase + (srow - 64) * 128;
            int r7 = srow & 7;
#pragma unroll
            for (int j = 0; j < 4; ++j) {
                bf16x8 v = *(const bf16x8*)(base + (((shalf * 4 + j) ^ r7) << 4));
#pragma unroll
                for (int e = 0; e < 8; ++e) {
                    float f = b2f((u16)v[e]);
                    ss += f * f;
                }
            }
        }
        __syncthreads();
        cur ^= 1;
    }

    ss += __shfl_xor(ss, 1);
    if (shalf == 0) {
        if (srow < 64) sumk[ch_ * 4096 + bn * 64 + srow] = ss;
        else           sumq[ch_ * 4096 + bn * 64 + srow - 64] = ss;
    }
    float* pp = part + ((long)bn * 8 + ch_) * 4096;
#pragma unroll
    for (int mf = 0; mf < 2; ++mf)
#pragma unroll
        for (int nf = 0; nf < 2; ++nf)
#pragma unroll
            for (int e = 0; e < 4; ++e) {
                int m = wm * 32 + mf * 16 + g * 4 + e;
                int nn = wn * 32 + nf * 16 + lr;
                pp[m * 64 + nn] = acc[mf][nf][e];
            }
}

// ---------------------------------------------------------------------------
// finalize: sum 8 partials, rsqrt norms, scale, softmax -> bf16  (R5)
// ---------------------------------------------------------------------------
__global__ __launch_bounds__(256) void attn_finalize_kernel(
    const float* __restrict__ part,  // [64][8][64][64]
    const float* __restrict__ sumq, const float* __restrict__ sumk, // [8][4096]
    const float* __restrict__ rescale,
    bf16* __restrict__ attn_out)
{
    const int bn = blockIdx.x;
    const int n = bn & 3;
    const int t = threadIdx.x;
    const float rs = rescale[n];

    __shared__ float att[64][65];
    __shared__ float rmax[64], rsum[64];
    __shared__ float iq[64], ik[64];

    if (t < 64) {
        float s = 0.f;
#pragma unroll
        for (int c = 0; c < 8; ++c) s += sumk[c * 4096 + bn * 64 + t];
        ik[t] = 1.f / fmaxf(sqrtf(s), 1e-12f);
    } else if (t < 128) {
        float s = 0.f;
#pragma unroll
        for (int c = 0; c < 8; ++c) s += sumq[c * 4096 + bn * 64 + t - 64];
        iq[t - 64] = 1.f / fmaxf(sqrtf(s), 1e-12f);
    }
    __syncthreads();

    const float* pb = part + (size_t)bn * 8 * 4096;
#pragma unroll
    for (int p = 0; p < 16; ++p) {
        int lin = p * 256 + t;
        int dd = lin >> 6, e = lin & 63;
        float v = 0.f;
#pragma unroll
        for (int c = 0; c < 8; ++c) v += pb[c * 4096 + lin];
        v *= ik[dd] * iq[e] * rs;
        att[dd][e] = v;
    }
    __syncthreads();
    if (t < 64) {
        float m = -1e30f;
        for (int e = 0; e < 64; ++e) m = fmaxf(m, att[t][e]);
        float sm = 0.f;
        for (int e = 0; e < 64; ++e) sm += expf(att[t][e] - m);
        rmax[t] = m;
        rsum[t] = 1.0f / sm;
    }
    __syncthreads();
    bf16* ob = attn_out + (size_t)bn * 4096;
#pragma unroll
    for (int p = 0; p < 16; ++p) {
        int lin = p * 256 + t;
        int dd = lin >> 6, e = lin & 63;
        ob[lin] = __float2bfloat16(expf(att[dd][e] - rmax[dd]) * rsum[dd]);
    }
}

// ---------------------------------------------------------------------------
// Fused PV + FFN, prefetched: 2 barriers per head. (R5)
// grid (32 s-tiles, 16 b), block 256.
// ---------------------------------------------------------------------------
__global__ __launch_bounds__(256) void pvffn(
    const bf16* __restrict__ vT,    // [64][4096][64]
    const bf16* __restrict__ attnb, // [64][64][64]
    const bf16* __restrict__ qch,   // [16][256][4096]
    const bf16* __restrict__ Wf,    // [256][256]
    const float* __restrict__ bffn, // [256]
    float* __restrict__ out)        // [16][256][4096]
{
    __shared__ bf16 bufA[2][12288]; // per buf: [0:8192) vT tile, [8192:12288) attn
    __shared__ bf16 Zs[128 * 64];   // XOR-swizzled
    const int t = threadIdx.x;
    const int lane = t & 63, wid = t >> 6;
    const int g = lane >> 4, lr = lane & 15;
    const int s0 = blockIdx.x * 128;
    const int b = blockIdx.y;

    f32x4 accF[4][8];
#pragma unroll
    for (int i = 0; i < 4; ++i)
#pragma unroll
        for (int j = 0; j < 8; ++j) accF[i][j] = (f32x4){0.f, 0.f, 0.f, 0.f};

    {
        const int bn = b * 4;
#pragma unroll
        for (int i = 0; i < 4; ++i) {
            int lin = i * 256 + t, r = lin >> 3, c = lin & 7;
            gl_lds16(vT + (long)bn * 262144 + (long)(s0 + r) * 64 + ((c ^ (r & 7)) << 3),
                     &bufA[0][lin * 8]);
        }
#pragma unroll
        for (int i = 0; i < 2; ++i) {
            int lin = i * 256 + t, r = lin >> 3, c = lin & 7;
            gl_lds16(attnb + (long)bn * 4096 + r * 64 + ((c ^ (r & 7)) << 3),
                     &bufA[0][8192 + lin * 8]);
        }
        __syncthreads();
    }

    for (int n = 0; n < 4; ++n) {
        const int bn = b * 4 + n;
        const int cur = n & 1;
        if (n < 3) {
            const int bnn = bn + 1;
#pragma unroll
            for (int i = 0; i < 4; ++i) {
                int lin = i * 256 + t, r = lin >> 3, c = lin & 7;
                gl_lds16(vT + (long)bnn * 262144 + (long)(s0 + r) * 64 + ((c ^ (r & 7)) << 3),
                         &bufA[cur ^ 1][lin * 8]);
            }
#pragma unroll
            for (int i = 0; i < 2; ++i) {
                int lin = i * 256 + t, r = lin >> 3, c = lin & 7;
                gl_lds16(attnb + (long)bnn * 4096 + r * 64 + ((c ^ (r & 7)) << 3),
                         &bufA[cur ^ 1][8192 + lin * 8]);
            }
        }
        bf16x8 wf[2][4];
#pragma unroll
        for (int kk = 0; kk < 2; ++kk)
#pragma unroll
            for (int mf = 0; mf < 4; ++mf)
                wf[kk][mf] = *(const bf16x8*)(
                    Wf + (long)(wid * 64 + mf * 16 + lr) * 256 + n * 64 + (kk * 4 + g) * 8);

        const char* vb = (const char*)&bufA[cur][0];
        const char* ab = vb + 16384;
        f32x4 accP[2][4];
#pragma unroll
        for (int i = 0; i < 2; ++i)
#pragma unroll
            for (int j = 0; j < 4; ++j) accP[i][j] = (f32x4){0.f, 0.f, 0.f, 0.f};
#pragma unroll
        for (int kk = 0; kk < 2; ++kk) {
            bf16x8 av[2], at[4];
#pragma unroll
            for (int mf = 0; mf < 2; ++mf) {
                int r = wid * 32 + mf * 16 + lr;
                av[mf] = *(const bf16x8*)(vb + r * 128 + (((kk * 4 + g) ^ (r & 7)) << 4));
            }
#pragma unroll
            for (int nf = 0; nf < 4; ++nf) {
                int r = nf * 16 + lr;
                at[nf] = *(const bf16x8*)(ab + r * 128 + (((kk * 4 + g) ^ (r & 7)) << 4));
            }
#pragma unroll
            for (int mf = 0; mf < 2; ++mf)
#pragma unroll
                for (int nf = 0; nf < 4; ++nf)
                    accP[mf][nf] = __builtin_amdgcn_mfma_f32_16x16x32_bf16(
                        av[mf], at[nf], accP[mf][nf], 0, 0, 0);
        }
#pragma unroll
        for (int mf = 0; mf < 2; ++mf)
#pragma unroll
            for (int nf = 0; nf < 4; ++nf) {
                int slb = wid * 32 + mf * 16 + g * 4;
                int il = nf * 16 + lr;
                ushort4 qv = *(const ushort4*)(qch + ((long)b * 256 + n * 64 + il) * 4096 + s0 + slb);
                u16 qa[4] = {qv.x, qv.y, qv.z, qv.w};
#pragma unroll
                for (int e = 0; e < 4; ++e) {
                    int sl = slb + e;
                    float v = accP[mf][nf][e] + b2f(qa[e]);
                    bf16 hv = __float2bfloat16(v);
                    int byte = sl * 128 + ((((il >> 3) ^ (sl & 7))) << 4) + (il & 7) * 2;
                    *(u16*)((char*)Zs + byte) = *(u16*)&hv;
                }
            }
        __syncthreads();   // B1: Zs visible; prefetch drained
#pragma unroll
        for (int kk = 0; kk < 2; ++kk) {
            bf16x8 bz[8];
#pragma unroll
            for (int nf = 0; nf < 8; ++nf) {
                int sl = nf * 16 + lr;
                bz[nf] = *(const bf16x8*)((const char*)Zs + sl * 128 + (((kk * 4 + g) ^ (sl & 7)) << 4));
            }
#pragma unroll
            for (int mf = 0; mf < 4; ++mf)
#pragma unroll
                for (int nf = 0; nf < 8; ++nf)
                    accF[mf][nf] = __builtin_amdgcn_mfma_f32_16x16x32_bf16(
                        wf[kk][mf], bz[nf], accF[mf][nf], 0, 0, 0);
        }
        __syncthreads();   // B2: FFN reads done before next head's Zs writes
    }

    float* ob = out + (long)b * 1048576;
    const bf16* qb = qch + (long)b * 1048576;
#pragma unroll
    for (int mf = 0; mf < 4; ++mf)
#pragma unroll
        for (int e = 0; e < 4; ++e) {
            int c = wid * 64 + mf * 16 + g * 4 + e;
            float bv = bffn[c];
#pragma unroll
            for (int nf = 0; nf < 8; ++nf) {
                int s = s0 + nf * 16 + lr;
                long idx = (long)c * 4096 + s;
                ob[idx] = accF[mf][nf][e] + bv + b2f(*(const u16*)(qb + idx));
            }
        }
}

// ---------------------------------------------------------------------------
__global__ __launch_bounds__(256) void wconv(
    const float* __restrict__ a, const float* __restrict__ b,
    const float* __restrict__ c, const float* __restrict__ d,
    bf16* __restrict__ o)
{
    int i = blockIdx.x * 256 + threadIdx.x;
    int which = i >> 16, off = i & 65535;
    const float* s = (which == 0) ? a : (which == 1) ? b : (which == 2) ? c : d;
    o[i] = __float2bfloat16(s[off]);
}

// ---------------------------------------------------------------------------
extern "C" void kernel_launch(void* const* d_in, const int* in_sizes, int n_in,
                              void* d_out, int out_size, void* d_ws, size_t ws_size,
                              hipStream_t stream) {
    const float* x       = (const float*)d_in[0];
    const float* fmaps   = (const float*)d_in[1];
    const float* Wq      = (const float*)d_in[2];
    const float* Wk      = (const float*)d_in[3];
    const float* Wv      = (const float*)d_in[4];
    const float* rescale = (const float*)d_in[5];
    const float* Wffn    = (const float*)d_in[6];
    const float* bffn    = (const float*)d_in[7];
    float* out = (float*)d_out;

    char* w = (char*)d_ws;
    bf16* kbuf  = (bf16*)(w + 0);             // 33.55 MB
    bf16* vT    = (bf16*)(w + 33554432L);     // 33.55 MB
    bf16* qch   = (bf16*)(w + 67108864L);     // 33.55 MB
    float* part = (float*)(w + 100663296L);   // 64*8*4096*4 = 8.39 MB
    bf16* attnb = (bf16*)(w + 109051904L);    // 512 KB
    float* sumq = (float*)(w + 109576192L);   // 8*4096*4 = 128 KB
    float* sumk = (float*)(w + 109707264L);   // 128 KB
    bf16* Wq_b  = (bf16*)(w + 109838336L);
    bf16* Wk_b  = Wq_b + 65536;
    bf16* Wv_b  = Wq_b + 131072;
    bf16* Wf_b  = Wq_b + 196608;

    dim3 blk(256);

    // 1. weights -> bf16
    wconv<<<dim3(1024), blk, 0, stream>>>(Wq, Wk, Wv, Wffn, Wq_b);
    // 2. K/V projections, fmaps read once
    kvproj<<<dim3(32, 64), blk, 0, stream>>>(fmaps, Wk_b, Wv_b, kbuf, vT);
    // 3. Q projection (256-o tile: x read once)
    qproj8<<<dim3(32, 16), dim3(512), 0, stream>>>(x, Wq_b, qch);
    // 4. QK^T partials + fused row sumsq (8 chunks, no atomics)
    qk_sum<<<dim3(8, 64), blk, 0, stream>>>(kbuf, qch, part, sumq, sumk);
    // 5. finalize: rsqrt + scale + softmax -> attn bf16
    attn_finalize_kernel<<<dim3(64), blk, 0, stream>>>(part, sumq, sumk, rescale, attnb);
    // 6. fused PV + FFN -> out f32
    pvffn<<<dim3(32, 16), blk, 0, stream>>>(vT, attnb, qch, Wf_b, bffn, out);
}

// Round 10
// 179.496 us; speedup vs baseline: 1.2288x; 1.0251x over previous
//
#include <hip/hip_runtime.h>
#include <hip/hip_bf16.h>
#include <cmath>

using bf16 = __hip_bfloat16;
typedef __attribute__((ext_vector_type(4))) float  f32x4;
typedef __attribute__((ext_vector_type(8))) short  bf16x8;
typedef unsigned int u32;
typedef unsigned short u16;

// async global->LDS, 16B per lane
__device__ __forceinline__ void gl_lds16(const bf16* g, bf16* l) {
    __builtin_amdgcn_global_load_lds(
        (const __attribute__((address_space(1))) u32*)g,
        (__attribute__((address_space(3))) u32*)l, 16, 0, 0);
}

__device__ __forceinline__ u32 pk2(float a, float b) {
    bf16 ha = __float2bfloat16(a), hb = __float2bfloat16(b);
    return (u32)*(u16*)&ha | ((u32)*(u16*)&hb << 16);
}
__device__ __forceinline__ float b2f(u16 v) {
    return __uint_as_float((u32)v << 16);
}

// ---------------------------------------------------------------------------
// Q projection: full 256-o tile (x read ONCE), fused transpose-convert. (R9)
// grid (32 s-tiles, 16 b), block 512.
// ---------------------------------------------------------------------------
__global__ __launch_bounds__(512) void qproj8(
    const float* __restrict__ x,   // [16][256][4096]
    const bf16* __restrict__ Wq,   // [256][256]
    bf16* __restrict__ qch)        // [16][256][4096]
{
    __shared__ __align__(16) bf16 sW[256 * 64];
    __shared__ __align__(16) bf16 sX[128 * 72];
    const int t = threadIdx.x;
    const int lane = t & 63, wid = t >> 6;
    const int wm = wid >> 1, wn = wid & 1;
    const int g = lane >> 4, lr = lane & 15;
    const int s0 = blockIdx.x * 128;
    const int b = blockIdx.y;
    const float* xb = x + (long)b * 1048576;

    f32x4 acc[4][4];
#pragma unroll
    for (int i = 0; i < 4; ++i)
#pragma unroll
        for (int j = 0; j < 4; ++j) acc[i][j] = (f32x4){0.f, 0.f, 0.f, 0.f};

    const int p  = t & 31;
    const int sl = t >> 5;

    for (int c0 = 0; c0 < 256; c0 += 64) {
        __syncthreads();
#pragma unroll
        for (int i = 0; i < 4; ++i) {
            int lin = i * 512 + t, r = lin >> 3, ch = lin & 7;
            gl_lds16(Wq + (long)r * 256 + c0 + ((ch ^ (r & 7)) << 3), &sW[lin * 8]);
        }
#pragma unroll
        for (int j = 0; j < 2; ++j) {
            int s4 = j * 16 + sl;
            const float* src = xb + (long)(c0 + 2 * p) * 4096 + s0 + s4 * 4;
            float4 a = *(const float4*)src;
            float4 bq = *(const float4*)(src + 4096);
            char* base = (char*)sX + p * 4 + (s4 * 4) * 144;
            *(u32*)(base +   0) = pk2(a.x, bq.x);
            *(u32*)(base + 144) = pk2(a.y, bq.y);
            *(u32*)(base + 288) = pk2(a.z, bq.z);
            *(u32*)(base + 432) = pk2(a.w, bq.w);
        }
        __syncthreads();
#pragma unroll
        for (int kk = 0; kk < 2; ++kk) {
            bf16x8 aw[4], fx[4];
#pragma unroll
            for (int mf = 0; mf < 4; ++mf) {
                int r = wm * 64 + mf * 16 + lr;
                aw[mf] = *(const bf16x8*)((const char*)sW + r * 128 + (((kk * 4 + g) ^ (r & 7)) << 4));
            }
#pragma unroll
            for (int nf = 0; nf < 4; ++nf) {
                int s = wn * 64 + nf * 16 + lr;
                fx[nf] = *(const bf16x8*)((const char*)sX + s * 144 + (kk * 4 + g) * 16);
            }
#pragma unroll
            for (int mf = 0; mf < 4; ++mf)
#pragma unroll
                for (int nf = 0; nf < 4; ++nf)
                    acc[mf][nf] = __builtin_amdgcn_mfma_f32_16x16x32_bf16(
                        aw[mf], fx[nf], acc[mf][nf], 0, 0, 0);
        }
    }
    bf16* qb = qch + (long)b * 1048576;
#pragma unroll
    for (int mf = 0; mf < 4; ++mf)
#pragma unroll
        for (int nf = 0; nf < 4; ++nf)
#pragma unroll
            for (int e = 0; e < 4; ++e) {
                int o = wm * 64 + mf * 16 + g * 4 + e;
                int s = s0 + wn * 64 + nf * 16 + lr;
                qb[(long)o * 4096 + s] = __float2bfloat16(acc[mf][nf][e]);
            }
}

// ---------------------------------------------------------------------------
// K+V projection, fused transpose-convert of fmaps, double-buffered. (R5)
// grid (32 s-tiles, 64 bn), block 256.
// ---------------------------------------------------------------------------
__global__ __launch_bounds__(256) void kvproj(
    const float* __restrict__ fm,  // [64][256][4096]
    const bf16* __restrict__ Wk,   // [4][64][256]
    const bf16* __restrict__ Wv,   // [4][64][256]
    bf16* __restrict__ kb,         // [64][64][4096]
    bf16* __restrict__ vT)         // [64][4096][64]
{
    __shared__ bf16 sF[2][128 * 72];
    __shared__ bf16 sK[2][64 * 64];
    __shared__ bf16 sV[2][64 * 64];
    const int t = threadIdx.x;
    const int lane = t & 63, wid = t >> 6;
    const int g = lane >> 4, lr = lane & 15;
    const int s0 = blockIdx.x * 128;
    const int bn = blockIdx.y, n = bn & 3;
    const float* fb = fm + (long)bn * 1048576;
    const bf16* WkN = Wk + (long)n * 16384;
    const bf16* WvN = Wv + (long)n * 16384;

    f32x4 acc1[4][2];
    f32x4 acc2[2][4];
#pragma unroll
    for (int i = 0; i < 4; ++i)
#pragma unroll
        for (int j = 0; j < 2; ++j) {
            acc1[i][j] = (f32x4){0.f, 0.f, 0.f, 0.f};
            acc2[j][i] = (f32x4){0.f, 0.f, 0.f, 0.f};
        }

    const int p  = t & 31;
    const int sl = t >> 5;

    {
#pragma unroll
        for (int i = 0; i < 2; ++i) {
            int lin = i * 256 + t, r = lin >> 3, ch = lin & 7;
            int off = r * 256 + ((ch ^ (r & 7)) << 3);
            gl_lds16(WkN + off, &sK[0][lin * 8]);
            gl_lds16(WvN + off, &sV[0][lin * 8]);
        }
        float4 ra[4], rb[4];
#pragma unroll
        for (int j = 0; j < 4; ++j) {
            const float* src = fb + (long)(2 * p) * 4096 + s0 + (j * 8 + sl) * 4;
            ra[j] = *(const float4*)src;
            rb[j] = *(const float4*)(src + 4096);
        }
#pragma unroll
        for (int j = 0; j < 4; ++j) {
            char* base = (char*)&sF[0][0] + p * 4 + ((j * 8 + sl) * 4) * 144;
            *(u32*)(base +   0) = pk2(ra[j].x, rb[j].x);
            *(u32*)(base + 144) = pk2(ra[j].y, rb[j].y);
            *(u32*)(base + 288) = pk2(ra[j].z, rb[j].z);
            *(u32*)(base + 432) = pk2(ra[j].w, rb[j].w);
        }
        __syncthreads();
    }

    int cur = 0;
    for (int it = 0; it < 4; ++it) {
        const int c0n = (it + 1) * 64;
        float4 ra[4], rb[4];
        if (it < 3) {
#pragma unroll
            for (int i = 0; i < 2; ++i) {
                int lin = i * 256 + t, r = lin >> 3, ch = lin & 7;
                int off = r * 256 + c0n + ((ch ^ (r & 7)) << 3);
                gl_lds16(WkN + off, &sK[cur ^ 1][lin * 8]);
                gl_lds16(WvN + off, &sV[cur ^ 1][lin * 8]);
            }
#pragma unroll
            for (int j = 0; j < 4; ++j) {
                const float* src = fb + (long)(c0n + 2 * p) * 4096 + s0 + (j * 8 + sl) * 4;
                ra[j] = *(const float4*)src;
                rb[j] = *(const float4*)(src + 4096);
            }
        }
        const char* fbase = (const char*)&sF[cur][0];
        const char* kbase = (const char*)&sK[cur][0];
        const char* vbase = (const char*)&sV[cur][0];
#pragma unroll
        for (int kk = 0; kk < 2; ++kk) {
            bf16x8 ak[4], ff[2], bv[4];
#pragma unroll
            for (int mf = 0; mf < 4; ++mf) {
                int r = mf * 16 + lr;
                ak[mf] = *(const bf16x8*)(kbase + r * 128 + (((kk * 4 + g) ^ (r & 7)) << 4));
            }
#pragma unroll
            for (int i = 0; i < 2; ++i) {
                int s = wid * 32 + i * 16 + lr;
                ff[i] = *(const bf16x8*)(fbase + s * 144 + (kk * 4 + g) * 16);
            }
#pragma unroll
            for (int nf = 0; nf < 4; ++nf) {
                int r = nf * 16 + lr;
                bv[nf] = *(const bf16x8*)(vbase + r * 128 + (((kk * 4 + g) ^ (r & 7)) << 4));
            }
#pragma unroll
            for (int mf = 0; mf < 4; ++mf)
#pragma unroll
                for (int i = 0; i < 2; ++i)
                    acc1[mf][i] = __builtin_amdgcn_mfma_f32_16x16x32_bf16(
                        ak[mf], ff[i], acc1[mf][i], 0, 0, 0);
#pragma unroll
            for (int i = 0; i < 2; ++i)
#pragma unroll
                for (int nf = 0; nf < 4; ++nf)
                    acc2[i][nf] = __builtin_amdgcn_mfma_f32_16x16x32_bf16(
                        ff[i], bv[nf], acc2[i][nf], 0, 0, 0);
        }
        if (it < 3) {
#pragma unroll
            for (int j = 0; j < 4; ++j) {
                char* base = (char*)&sF[cur ^ 1][0] + p * 4 + ((j * 8 + sl) * 4) * 144;
                *(u32*)(base +   0) = pk2(ra[j].x, rb[j].x);
                *(u32*)(base + 144) = pk2(ra[j].y, rb[j].y);
                *(u32*)(base + 288) = pk2(ra[j].z, rb[j].z);
                *(u32*)(base + 432) = pk2(ra[j].w, rb[j].w);
            }
            __syncthreads();
            cur ^= 1;
        }
    }

    bf16* kbb = kb + (long)bn * 262144;
#pragma unroll
    for (int mf = 0; mf < 4; ++mf)
#pragma unroll
        for (int i = 0; i < 2; ++i)
#pragma unroll
            for (int e = 0; e < 4; ++e) {
                int dd = mf * 16 + g * 4 + e;
                int s  = s0 + wid * 32 + i * 16 + lr;
                kbb[(long)dd * 4096 + s] = __float2bfloat16(acc1[mf][i][e]);
            }
    bf16* vtb = vT + (long)bn * 262144;
#pragma unroll
    for (int i = 0; i < 2; ++i)
#pragma unroll
        for (int nf = 0; nf < 4; ++nf)
#pragma unroll
            for (int e = 0; e < 4; ++e) {
                int s = s0 + wid * 32 + i * 16 + g * 4 + e;
                int ec = nf * 16 + lr;
                vtb[(long)s * 64 + ec] = __float2bfloat16(acc2[i][nf][e]);
            }
}

// ---------------------------------------------------------------------------
// QK^T partial + fused row sum-of-squares, 8 chunks, double-buffered. (R5)
// grid (8, 64), block 256.
// ---------------------------------------------------------------------------
__global__ __launch_bounds__(256) void qk_sum(
    const bf16* __restrict__ kb,   // [64][64][4096]
    const bf16* __restrict__ qch,  // viewed as [64][64][4096]
    float* __restrict__ part,      // [64][8][64][64]
    float* __restrict__ sumq, float* __restrict__ sumk)  // [8][4096]
{
    __shared__ bf16 sA[2][64 * 64];
    __shared__ bf16 sB[2][64 * 64];
    const int t = threadIdx.x;
    const int lane = t & 63, wid = t >> 6;
    const int wm = wid >> 1, wn = wid & 1;
    const int g = lane >> 4, lr = lane & 15;
    const int ch_ = blockIdx.x;
    const int bn = blockIdx.y;
    const bf16* kbase = kb + (long)bn * 262144;
    const bf16* qbase = qch + (long)bn * 262144;

    const int srow = t >> 1;
    const int shalf = t & 1;

    f32x4 acc[2][2];
#pragma unroll
    for (int i = 0; i < 2; ++i)
#pragma unroll
        for (int j = 0; j < 2; ++j) acc[i][j] = (f32x4){0.f, 0.f, 0.f, 0.f};
    float ss = 0.f;

    {
        int k0 = ch_ * 512;
#pragma unroll
        for (int i = 0; i < 2; ++i) {
            int lin = i * 256 + t, r = lin >> 3, c = lin & 7;
            gl_lds16(kbase + (long)r * 4096 + k0 + ((c ^ (r & 7)) << 3), &sA[0][lin * 8]);
            gl_lds16(qbase + (long)r * 4096 + k0 + ((c ^ (r & 7)) << 3), &sB[0][lin * 8]);
        }
        __syncthreads();
    }

    int cur = 0;
    for (int it = 0; it < 8; ++it) {
        if (it < 7) {
            int k0 = ch_ * 512 + (it + 1) * 64;
#pragma unroll
            for (int i = 0; i < 2; ++i) {
                int lin = i * 256 + t, r = lin >> 3, c = lin & 7;
                gl_lds16(kbase + (long)r * 4096 + k0 + ((c ^ (r & 7)) << 3), &sA[cur ^ 1][lin * 8]);
                gl_lds16(qbase + (long)r * 4096 + k0 + ((c ^ (r & 7)) << 3), &sB[cur ^ 1][lin * 8]);
            }
        }
        const char* abase = (const char*)&sA[cur][0];
        const char* bbase = (const char*)&sB[cur][0];
#pragma unroll
        for (int kk = 0; kk < 2; ++kk) {
            bf16x8 af[2], bf[2];
#pragma unroll
            for (int mf = 0; mf < 2; ++mf) {
                int r = wm * 32 + mf * 16 + lr;
                af[mf] = *(const bf16x8*)(abase + r * 128 + (((kk * 4 + g) ^ (r & 7)) << 4));
            }
#pragma unroll
            for (int nf = 0; nf < 2; ++nf) {
                int r = wn * 32 + nf * 16 + lr;
                bf[nf] = *(const bf16x8*)(bbase + r * 128 + (((kk * 4 + g) ^ (r & 7)) << 4));
            }
#pragma unroll
            for (int mf = 0; mf < 2; ++mf)
#pragma unroll
                for (int nf = 0; nf < 2; ++nf)
                    acc[mf][nf] = __builtin_amdgcn_mfma_f32_16x16x32_bf16(
                        af[mf], bf[nf], acc[mf][nf], 0, 0, 0);
        }
        {
            const char* base = (srow < 64) ? abase + srow * 128
                                           : bbase + (srow - 64) * 128;
            int r7 = srow & 7;
#pragma unroll
            for (int j = 0; j < 4; ++j) {
                bf16x8 v = *(const bf16x8*)(base + (((shalf * 4 + j) ^ r7) << 4));
#pragma unroll
                for (int e = 0; e < 8; ++e) {
                    float f = b2f((u16)v[e]);
                    ss += f * f;
                }
            }
        }
        __syncthreads();
        cur ^= 1;
    }

    ss += __shfl_xor(ss, 1);
    if (shalf == 0) {
        if (srow < 64) sumk[ch_ * 4096 + bn * 64 + srow] = ss;
        else           sumq[ch_ * 4096 + bn * 64 + srow - 64] = ss;
    }
    float* pp = part + ((long)bn * 8 + ch_) * 4096;
#pragma unroll
    for (int mf = 0; mf < 2; ++mf)
#pragma unroll
        for (int nf = 0; nf < 2; ++nf)
#pragma unroll
            for (int e = 0; e < 4; ++e) {
                int m = wm * 32 + mf * 16 + g * 4 + e;
                int nn = wn * 32 + nf * 16 + lr;
                pp[m * 64 + nn] = acc[mf][nf][e];
            }
}

// ---------------------------------------------------------------------------
// finalize: sum 8 partials, rsqrt norms, scale, softmax -> bf16  (R5)
// ---------------------------------------------------------------------------
__global__ __launch_bounds__(256) void attn_finalize_kernel(
    const float* __restrict__ part,
    const float* __restrict__ sumq, const float* __restrict__ sumk,
    const float* __restrict__ rescale,
    bf16* __restrict__ attn_out)
{
    const int bn = blockIdx.x;
    const int n = bn & 3;
    const int t = threadIdx.x;
    const float rs = rescale[n];

    __shared__ float att[64][65];
    __shared__ float rmax[64], rsum[64];
    __shared__ float iq[64], ik[64];

    if (t < 64) {
        float s = 0.f;
#pragma unroll
        for (int c = 0; c < 8; ++c) s += sumk[c * 4096 + bn * 64 + t];
        ik[t] = 1.f / fmaxf(sqrtf(s), 1e-12f);
    } else if (t < 128) {
        float s = 0.f;
#pragma unroll
        for (int c = 0; c < 8; ++c) s += sumq[c * 4096 + bn * 64 + t - 64];
        iq[t - 64] = 1.f / fmaxf(sqrtf(s), 1e-12f);
    }
    __syncthreads();

    const float* pb = part + (size_t)bn * 8 * 4096;
#pragma unroll
    for (int p = 0; p < 16; ++p) {
        int lin = p * 256 + t;
        int dd = lin >> 6, e = lin & 63;
        float v = 0.f;
#pragma unroll
        for (int c = 0; c < 8; ++c) v += pb[c * 4096 + lin];
        v *= ik[dd] * iq[e] * rs;
        att[dd][e] = v;
    }
    __syncthreads();
    if (t < 64) {
        float m = -1e30f;
        for (int e = 0; e < 64; ++e) m = fmaxf(m, att[t][e]);
        float sm = 0.f;
        for (int e = 0; e < 64; ++e) sm += expf(att[t][e] - m);
        rmax[t] = m;
        rsum[t] = 1.0f / sm;
    }
    __syncthreads();
    bf16* ob = attn_out + (size_t)bn * 4096;
#pragma unroll
    for (int p = 0; p < 16; ++p) {
        int lin = p * 256 + t;
        int dd = lin >> 6, e = lin & 63;
        ob[lin] = __float2bfloat16(expf(att[dd][e] - rmax[dd]) * rsum[dd]);
    }
}

// ---------------------------------------------------------------------------
// Fused PV + FFN, prefetched, 64-s tile for occupancy (3-4 blocks/CU).
// grid (64 s-tiles, 16 b), block 256. LDS 40 KB.
// ---------------------------------------------------------------------------
__global__ __launch_bounds__(256) void pvffn(
    const bf16* __restrict__ vT,    // [64][4096][64]
    const bf16* __restrict__ attnb, // [64][64][64]
    const bf16* __restrict__ qch,   // [16][256][4096]
    const bf16* __restrict__ Wf,    // [256][256]
    const float* __restrict__ bffn, // [256]
    float* __restrict__ out)        // [16][256][4096]
{
    __shared__ bf16 bufA[2][8192]; // per buf: [0:4096) vT tile, [4096:8192) attn
    __shared__ bf16 Zs[64 * 64];   // XOR-swizzled
    const int t = threadIdx.x;
    const int lane = t & 63, wid = t >> 6;
    const int g = lane >> 4, lr = lane & 15;
    const int s0 = blockIdx.x * 64;
    const int b = blockIdx.y;

    f32x4 accF[4][4];
#pragma unroll
    for (int i = 0; i < 4; ++i)
#pragma unroll
        for (int j = 0; j < 4; ++j) accF[i][j] = (f32x4){0.f, 0.f, 0.f, 0.f};

    // prologue: stage head 0 (vT 64x64 + attn 64x64)
    {
        const int bn = b * 4;
#pragma unroll
        for (int i = 0; i < 2; ++i) {
            int lin = i * 256 + t, r = lin >> 3, c = lin & 7;
            gl_lds16(vT + (long)bn * 262144 + (long)(s0 + r) * 64 + ((c ^ (r & 7)) << 3),
                     &bufA[0][lin * 8]);
            gl_lds16(attnb + (long)bn * 4096 + r * 64 + ((c ^ (r & 7)) << 3),
                     &bufA[0][4096 + lin * 8]);
        }
        __syncthreads();
    }

    for (int n = 0; n < 4; ++n) {
        const int bn = b * 4 + n;
        const int cur = n & 1;
        if (n < 3) {
            const int bnn = bn + 1;
#pragma unroll
            for (int i = 0; i < 2; ++i) {
                int lin = i * 256 + t, r = lin >> 3, c = lin & 7;
                gl_lds16(vT + (long)bnn * 262144 + (long)(s0 + r) * 64 + ((c ^ (r & 7)) << 3),
                         &bufA[cur ^ 1][lin * 8]);
                gl_lds16(attnb + (long)bnn * 4096 + r * 64 + ((c ^ (r & 7)) << 3),
                         &bufA[cur ^ 1][4096 + lin * 8]);
            }
        }
        // Wf fragments (L2-resident)
        bf16x8 wf[2][4];
#pragma unroll
        for (int kk = 0; kk < 2; ++kk)
#pragma unroll
            for (int mf = 0; mf < 4; ++mf)
                wf[kk][mf] = *(const bf16x8*)(
                    Wf + (long)(wid * 64 + mf * 16 + lr) * 256 + n * 64 + (kk * 4 + g) * 8);

        // PV: wave wid owns s-rows wid*16..+15
        const char* vb = (const char*)&bufA[cur][0];
        const char* ab = vb + 8192;
        f32x4 accP[4];
#pragma unroll
        for (int j = 0; j < 4; ++j) accP[j] = (f32x4){0.f, 0.f, 0.f, 0.f};
#pragma unroll
        for (int kk = 0; kk < 2; ++kk) {
            int r = wid * 16 + lr;
            bf16x8 av = *(const bf16x8*)(vb + r * 128 + (((kk * 4 + g) ^ (r & 7)) << 4));
            bf16x8 at[4];
#pragma unroll
            for (int nf = 0; nf < 4; ++nf) {
                int rr = nf * 16 + lr;
                at[nf] = *(const bf16x8*)(ab + rr * 128 + (((kk * 4 + g) ^ (rr & 7)) << 4));
            }
#pragma unroll
            for (int nf = 0; nf < 4; ++nf)
                accP[nf] = __builtin_amdgcn_mfma_f32_16x16x32_bf16(
                    av, at[nf], accP[nf], 0, 0, 0);
        }
        // write Z slice (+ q residual) into swizzled Zs
#pragma unroll
        for (int nf = 0; nf < 4; ++nf) {
            int slb = wid * 16 + g * 4;
            int il = nf * 16 + lr;
            ushort4 qv = *(const ushort4*)(qch + ((long)b * 256 + n * 64 + il) * 4096 + s0 + slb);
            u16 qa[4] = {qv.x, qv.y, qv.z, qv.w};
#pragma unroll
            for (int e = 0; e < 4; ++e) {
                int sl = slb + e;
                float v = accP[nf][e] + b2f(qa[e]);
                bf16 hv = __float2bfloat16(v);
                int byte = sl * 128 + ((((il >> 3) ^ (sl & 7))) << 4) + (il & 7) * 2;
                *(u16*)((char*)Zs + byte) = *(u16*)&hv;
            }
        }
        __syncthreads();   // B1: Zs visible; prefetch drained
        // FFN partial: wave wid owns c-rows wid*64..+63, all 64 s
#pragma unroll
        for (int kk = 0; kk < 2; ++kk) {
            bf16x8 bz[4];
#pragma unroll
            for (int nf = 0; nf < 4; ++nf) {
                int sl = nf * 16 + lr;
                bz[nf] = *(const bf16x8*)((const char*)Zs + sl * 128 + (((kk * 4 + g) ^ (sl & 7)) << 4));
            }
#pragma unroll
            for (int mf = 0; mf < 4; ++mf)
#pragma unroll
                for (int nf = 0; nf < 4; ++nf)
                    accF[mf][nf] = __builtin_amdgcn_mfma_f32_16x16x32_bf16(
                        wf[kk][mf], bz[nf], accF[mf][nf], 0, 0, 0);
        }
        __syncthreads();   // B2: FFN reads done before next head's Zs writes
    }

    float* ob = out + (long)b * 1048576;
    const bf16* qb = qch + (long)b * 1048576;
#pragma unroll
    for (int mf = 0; mf < 4; ++mf)
#pragma unroll
        for (int e = 0; e < 4; ++e) {
            int c = wid * 64 + mf * 16 + g * 4 + e;
            float bv = bffn[c];
#pragma unroll
            for (int nf = 0; nf < 4; ++nf) {
                int s = s0 + nf * 16 + lr;
                long idx = (long)c * 4096 + s;
                ob[idx] = accF[mf][nf][e] + bv + b2f(*(const u16*)(qb + idx));
            }
        }
}

// ---------------------------------------------------------------------------
__global__ __launch_bounds__(256) void wconv(
    const float* __restrict__ a, const float* __restrict__ b,
    const float* __restrict__ c, const float* __restrict__ d,
    bf16* __restrict__ o)
{
    int i = blockIdx.x * 256 + threadIdx.x;
    int which = i >> 16, off = i & 65535;
    const float* s = (which == 0) ? a : (which == 1) ? b : (which == 2) ? c : d;
    o[i] = __float2bfloat16(s[off]);
}

// ---------------------------------------------------------------------------
extern "C" void kernel_launch(void* const* d_in, const int* in_sizes, int n_in,
                              void* d_out, int out_size, void* d_ws, size_t ws_size,
                              hipStream_t stream) {
    const float* x       = (const float*)d_in[0];
    const float* fmaps   = (const float*)d_in[1];
    const float* Wq      = (const float*)d_in[2];
    const float* Wk      = (const float*)d_in[3];
    const float* Wv      = (const float*)d_in[4];
    const float* rescale = (const float*)d_in[5];
    const float* Wffn    = (const float*)d_in[6];
    const float* bffn    = (const float*)d_in[7];
    float* out = (float*)d_out;

    char* w = (char*)d_ws;
    bf16* kbuf  = (bf16*)(w + 0);             // 33.55 MB
    bf16* vT    = (bf16*)(w + 33554432L);     // 33.55 MB
    bf16* qch   = (bf16*)(w + 67108864L);     // 33.55 MB
    float* part = (float*)(w + 100663296L);   // 8.39 MB
    bf16* attnb = (bf16*)(w + 109051904L);    // 512 KB
    float* sumq = (float*)(w + 109576192L);   // 128 KB
    float* sumk = (float*)(w + 109707264L);   // 128 KB
    bf16* Wq_b  = (bf16*)(w + 109838336L);
    bf16* Wk_b  = Wq_b + 65536;
    bf16* Wv_b  = Wq_b + 131072;
    bf16* Wf_b  = Wq_b + 196608;

    dim3 blk(256);

    // 1. weights -> bf16
    wconv<<<dim3(1024), blk, 0, stream>>>(Wq, Wk, Wv, Wffn, Wq_b);
    // 2. K/V projections, fmaps read once
    kvproj<<<dim3(32, 64), blk, 0, stream>>>(fmaps, Wk_b, Wv_b, kbuf, vT);
    // 3. Q projection (256-o tile: x read once)
    qproj8<<<dim3(32, 16), dim3(512), 0, stream>>>(x, Wq_b, qch);
    // 4. QK^T partials + fused row sumsq
    qk_sum<<<dim3(8, 64), blk, 0, stream>>>(kbuf, qch, part, sumq, sumk);
    // 5. finalize: rsqrt + scale + softmax -> attn bf16
    attn_finalize_kernel<<<dim3(64), blk, 0, stream>>>(part, sumq, sumk, rescale, attnb);
    // 6. fused PV + FFN (64-s tile, 40 KB LDS) -> out f32
    pvffn<<<dim3(64, 16), blk, 0, stream>>>(vT, attnb, qch, Wf_b, bffn, out);
}